// Round 4
// baseline (359.315 us; speedup 1.0000x reference)
//
#include <hip/hip_runtime.h>

#define NB 512
#define NT 256
#define C_COLS 16

// ws layout (floats): partials[NB*32], mean[16], then 2 ints (count, flag).
__global__ void k_init(int* __restrict__ sync) {
    sync[0] = 0;  // arrival count
    sync[1] = 0;  // mean-ready flag
}

__global__ __launch_bounds__(NT, 4) void k_fused(const float4* __restrict__ x4,
                                                 float4* __restrict__ o4,
                                                 long long n4, long long n,
                                                 long long chunk,  // multiple of 4
                                                 float* __restrict__ partials,
                                                 float* __restrict__ meanbuf,
                                                 int* __restrict__ sync) {
    const int tid = threadIdx.x;
    const int b = blockIdx.x;
    const long long beg = (long long)b * chunk;
    long long end = beg + chunk;
    if (end > n4) end = n4;

    // ---------------- Phase 1: reduce own chunk ----------------
    float s0 = 0.f, s1 = 0.f, s2 = 0.f, s3 = 0.f;
    float c0 = 0.f, c1 = 0.f, c2 = 0.f, c3 = 0.f;

    long long i = beg + tid;
    for (; i + 3 * NT < end; i += 4 * NT) {
        float4 a = x4[i];
        float4 bb = x4[i + NT];
        float4 cc = x4[i + 2 * NT];
        float4 dd = x4[i + 3 * NT];
        bool m;
        m = (a.x == a.x);  s0 += m ? a.x : 0.f;  c0 += m ? 1.f : 0.f;
        m = (a.y == a.y);  s1 += m ? a.y : 0.f;  c1 += m ? 1.f : 0.f;
        m = (a.z == a.z);  s2 += m ? a.z : 0.f;  c2 += m ? 1.f : 0.f;
        m = (a.w == a.w);  s3 += m ? a.w : 0.f;  c3 += m ? 1.f : 0.f;
        m = (bb.x == bb.x); s0 += m ? bb.x : 0.f; c0 += m ? 1.f : 0.f;
        m = (bb.y == bb.y); s1 += m ? bb.y : 0.f; c1 += m ? 1.f : 0.f;
        m = (bb.z == bb.z); s2 += m ? bb.z : 0.f; c2 += m ? 1.f : 0.f;
        m = (bb.w == bb.w); s3 += m ? bb.w : 0.f; c3 += m ? 1.f : 0.f;
        m = (cc.x == cc.x); s0 += m ? cc.x : 0.f; c0 += m ? 1.f : 0.f;
        m = (cc.y == cc.y); s1 += m ? cc.y : 0.f; c1 += m ? 1.f : 0.f;
        m = (cc.z == cc.z); s2 += m ? cc.z : 0.f; c2 += m ? 1.f : 0.f;
        m = (cc.w == cc.w); s3 += m ? cc.w : 0.f; c3 += m ? 1.f : 0.f;
        m = (dd.x == dd.x); s0 += m ? dd.x : 0.f; c0 += m ? 1.f : 0.f;
        m = (dd.y == dd.y); s1 += m ? dd.y : 0.f; c1 += m ? 1.f : 0.f;
        m = (dd.z == dd.z); s2 += m ? dd.z : 0.f; c2 += m ? 1.f : 0.f;
        m = (dd.w == dd.w); s3 += m ? dd.w : 0.f; c3 += m ? 1.f : 0.f;
    }
    for (; i < end; i += NT) {
        float4 v = x4[i];
        bool m;
        m = (v.x == v.x); s0 += m ? v.x : 0.f; c0 += m ? 1.f : 0.f;
        m = (v.y == v.y); s1 += m ? v.y : 0.f; c1 += m ? 1.f : 0.f;
        m = (v.z == v.z); s2 += m ? v.z : 0.f; c2 += m ? 1.f : 0.f;
        m = (v.w == v.w); s3 += m ? v.w : 0.f; c3 += m ? 1.f : 0.f;
    }

    // beg%4==0 and NT%4==0 -> this thread's column group is (tid&3)*4.
    for (int off = 4; off < 64; off <<= 1) {
        s0 += __shfl_xor(s0, off, 64);
        s1 += __shfl_xor(s1, off, 64);
        s2 += __shfl_xor(s2, off, 64);
        s3 += __shfl_xor(s3, off, 64);
        c0 += __shfl_xor(c0, off, 64);
        c1 += __shfl_xor(c1, off, 64);
        c2 += __shfl_xor(c2, off, 64);
        c3 += __shfl_xor(c3, off, 64);
    }

    __shared__ float bsum[C_COLS];
    __shared__ float bcnt[C_COLS];
    if (tid < C_COLS) { bsum[tid] = 0.f; bcnt[tid] = 0.f; }
    __syncthreads();
    if ((tid & 63) < 4) {
        const int cb = (tid & 3) * 4;
        atomicAdd(&bsum[cb + 0], s0);
        atomicAdd(&bsum[cb + 1], s1);
        atomicAdd(&bsum[cb + 2], s2);
        atomicAdd(&bsum[cb + 3], s3);
        atomicAdd(&bcnt[cb + 0], c0);
        atomicAdd(&bcnt[cb + 1], c1);
        atomicAdd(&bcnt[cb + 2], c2);
        atomicAdd(&bcnt[cb + 3], c3);
    }
    __syncthreads();
    if (tid < C_COLS) {
        partials[b * 32 + tid]      = bsum[tid];
        partials[b * 32 + 16 + tid] = bcnt[tid];
    }
    __threadfence();  // device-scope release of partials

    // ---------------- Phase 2: arrival; last block computes mean ----------------
    __shared__ int ticket;
    if (tid == 0)
        ticket = __hip_atomic_fetch_add(&sync[0], 1, __ATOMIC_ACQ_REL,
                                        __HIP_MEMORY_SCOPE_AGENT);
    __syncthreads();

    if (ticket == NB - 1) {  // last-arriving block
        const int c = tid & 15;
        const int r0 = tid >> 4;
        float s = 0.f, cn = 0.f;
        for (int p = r0; p < NB; p += 16) {
            s  += __hip_atomic_load(&partials[p * 32 + c], __ATOMIC_RELAXED,
                                    __HIP_MEMORY_SCOPE_AGENT);
            cn += __hip_atomic_load(&partials[p * 32 + 16 + c], __ATOMIC_RELAXED,
                                    __HIP_MEMORY_SCOPE_AGENT);
        }
        __shared__ float ssum[NT];
        __shared__ float scnt[NT];
        ssum[tid] = s;
        scnt[tid] = cn;
        __syncthreads();
        if (tid < 16) {
            float S = 0.f, Cn = 0.f;
            for (int r = 0; r < 16; ++r) {
                S  += ssum[r * 16 + tid];
                Cn += scnt[r * 16 + tid];
            }
            const float* xs = (const float*)x4;
            for (long long j = n4 * 4; j < n; ++j) {  // scalar tail (unused here)
                if ((int)(j % 16) == tid) {
                    float v = xs[j];
                    if (v == v) { S += v; Cn += 1.f; }
                }
            }
            __hip_atomic_store(&meanbuf[tid], S / fmaxf(Cn, 1.f),
                               __ATOMIC_RELEASE, __HIP_MEMORY_SCOPE_AGENT);
        }
        __syncthreads();
        __threadfence();
        if (tid == 0)
            __hip_atomic_store(&sync[1], 1, __ATOMIC_RELEASE,
                               __HIP_MEMORY_SCOPE_AGENT);
    }

    // All blocks wait for the mean.
    if (tid == 0) {
        while (__hip_atomic_load(&sync[1], __ATOMIC_ACQUIRE,
                                 __HIP_MEMORY_SCOPE_AGENT) == 0) {
            __builtin_amdgcn_s_sleep(8);
        }
    }
    __syncthreads();

    const int cb = (tid & 3) * 4;
    const float m0 = __hip_atomic_load(&meanbuf[cb + 0], __ATOMIC_RELAXED,
                                       __HIP_MEMORY_SCOPE_AGENT);
    const float m1 = __hip_atomic_load(&meanbuf[cb + 1], __ATOMIC_RELAXED,
                                       __HIP_MEMORY_SCOPE_AGENT);
    const float m2 = __hip_atomic_load(&meanbuf[cb + 2], __ATOMIC_RELAXED,
                                       __HIP_MEMORY_SCOPE_AGENT);
    const float m3 = __hip_atomic_load(&meanbuf[cb + 3], __ATOMIC_RELAXED,
                                       __HIP_MEMORY_SCOPE_AGENT);

    // ---------------- Phase 3: fill own chunk (L3-hot) ----------------
    i = beg + tid;
    for (; i + 3 * NT < end; i += 4 * NT) {
        float4 a = x4[i];
        float4 bb = x4[i + NT];
        float4 cc = x4[i + 2 * NT];
        float4 dd = x4[i + 3 * NT];
        a.x = (a.x == a.x) ? a.x : m0;
        a.y = (a.y == a.y) ? a.y : m1;
        a.z = (a.z == a.z) ? a.z : m2;
        a.w = (a.w == a.w) ? a.w : m3;
        bb.x = (bb.x == bb.x) ? bb.x : m0;
        bb.y = (bb.y == bb.y) ? bb.y : m1;
        bb.z = (bb.z == bb.z) ? bb.z : m2;
        bb.w = (bb.w == bb.w) ? bb.w : m3;
        cc.x = (cc.x == cc.x) ? cc.x : m0;
        cc.y = (cc.y == cc.y) ? cc.y : m1;
        cc.z = (cc.z == cc.z) ? cc.z : m2;
        cc.w = (cc.w == cc.w) ? cc.w : m3;
        dd.x = (dd.x == dd.x) ? dd.x : m0;
        dd.y = (dd.y == dd.y) ? dd.y : m1;
        dd.z = (dd.z == dd.z) ? dd.z : m2;
        dd.w = (dd.w == dd.w) ? dd.w : m3;
        o4[i] = a;
        o4[i + NT] = bb;
        o4[i + 2 * NT] = cc;
        o4[i + 3 * NT] = dd;
    }
    for (; i < end; i += NT) {
        float4 v = x4[i];
        v.x = (v.x == v.x) ? v.x : m0;
        v.y = (v.y == v.y) ? v.y : m1;
        v.z = (v.z == v.z) ? v.z : m2;
        v.w = (v.w == v.w) ? v.w : m3;
        o4[i] = v;
    }

    if (b == 0 && tid == 0) {  // scalar tail (unused for this shape)
        const float* xs = (const float*)x4;
        float* os = (float*)o4;
        for (long long j = n4 * 4; j < n; ++j) {
            float v = xs[j];
            float mj = __hip_atomic_load(&meanbuf[(int)(j % 16)], __ATOMIC_RELAXED,
                                         __HIP_MEMORY_SCOPE_AGENT);
            os[j] = (v == v) ? v : mj;
        }
    }
}

extern "C" void kernel_launch(void* const* d_in, const int* in_sizes, int n_in,
                              void* d_out, int out_size, void* d_ws, size_t ws_size,
                              hipStream_t stream) {
    const float* x = (const float*)d_in[0];
    float* out = (float*)d_out;
    const long long n = (long long)in_sizes[0];
    const long long n4 = n / 4;

    float* partials = (float*)d_ws;                 // NB*32 floats
    float* meanbuf = partials + (long long)NB * 32; // 16 floats
    int* sync = (int*)(meanbuf + 16);               // 2 ints

    long long chunk = ((n4 + NB - 1) / NB + 3) & ~3LL;  // multiple of 4

    k_init<<<1, 1, 0, stream>>>(sync);
    k_fused<<<NB, NT, 0, stream>>>((const float4*)x, (float4*)out, n4, n, chunk,
                                   partials, meanbuf, sync);
}